// Round 14
// baseline (532.591 us; speedup 1.0000x reference)
//
#include <hip/hip_runtime.h>

#define GG 64    // num_graphs (fixed by problem)
#define SREP 32  // BN-stats replicas: spreads lane-atomics over 32x cache lines
#define BSH 14   // source-bucket shift: 16384-node tiles (2MB of 128B rows) -> L2-resident
typedef unsigned long long ull;
typedef unsigned short u16;
typedef unsigned int uint;

__device__ __forceinline__ u16 f2b(float x) {          // fp32 -> bf16 (RN-even)
    unsigned u = __float_as_uint(x);
    return (u16)((u + 0x7FFFu + ((u >> 16) & 1u)) >> 16);
}

// unpack uint4 (8 bf16) and ADD into acc[8]
__device__ __forceinline__ void add8(const uint4 q, float* acc) {
    acc[0] += __uint_as_float(q.x << 16);
    acc[1] += __uint_as_float(q.x & 0xFFFF0000u);
    acc[2] += __uint_as_float(q.y << 16);
    acc[3] += __uint_as_float(q.y & 0xFFFF0000u);
    acc[4] += __uint_as_float(q.z << 16);
    acc[5] += __uint_as_float(q.z & 0xFFFF0000u);
    acc[6] += __uint_as_float(q.w << 16);
    acc[7] += __uint_as_float(q.w & 0xFFFF0000u);
}

// ---------------- CSR build (bucketed by source tile) ----------------
// XCD-partitioned hist (fire-and-forget atomics; partition keeps lines L2-exclusive).
// [R11 lesson: fetch-add atomics write through (~60MB/1.6M RMWs) regardless of
//  partitioning; the 8x dst re-read here is L3-served and ~free (R6/R8/R11 evidence)]
__global__ __launch_bounds__(256) void k_hist(const int* __restrict__ src,
                                              const int* __restrict__ dst,
                                              int* __restrict__ cnt4, int E, int n) {
    const int part = blockIdx.x & 7;
    const int nblk = gridDim.x >> 3;
    const int bser = blockIdx.x >> 3;
    const int lo = (int)(((long long)part * n) >> 3);
    const int hi = (part == 7) ? n : (int)(((long long)(part + 1) * n) >> 3);
    for (int e = bser * 256 + threadIdx.x; e < E; e += nblk * 256) {
        int d = dst[e];
        if (d >= lo && d < hi) {
            int b = min(src[e] >> BSH, 7);
            atomicAdd(&cnt4[(d << 3) + b], 1);
        }
    }
}

// fused: degree+dis from cnt4, then intra-block exclusive scan (saves the k_sum4 pass)
__global__ void k_scanA(const int* __restrict__ cnt4, int* __restrict__ rp,
                        int* __restrict__ bsum, float* __restrict__ dis, int n) {
    __shared__ int s[256];
    int i = blockIdx.x * 256 + threadIdx.x;
    int v = 0;
    if (i < n) {
        #pragma unroll
        for (int b = 0; b < 8; ++b) v += cnt4[(i << 3) + b];
        dis[i] = rsqrtf((float)v + 1.0f);
    }
    s[threadIdx.x] = v;
    __syncthreads();
    for (int off = 1; off < 256; off <<= 1) {
        int t = (threadIdx.x >= off) ? s[threadIdx.x - off] : 0;
        __syncthreads();
        s[threadIdx.x] += t;
        __syncthreads();
    }
    if (i < n) rp[i] = s[threadIdx.x] - v;
    if (threadIdx.x == 255) bsum[blockIdx.x] = s[255];
}

__global__ void k_scanB(int* __restrict__ bsum, int nb) {
    __shared__ int s[512];
    int v = (threadIdx.x < nb) ? bsum[threadIdx.x] : 0;
    s[threadIdx.x] = v;
    __syncthreads();
    for (int off = 1; off < 512; off <<= 1) {
        int t = (threadIdx.x >= off) ? s[threadIdx.x - off] : 0;
        __syncthreads();
        s[threadIdx.x] += t;
        __syncthreads();
    }
    if (threadIdx.x < nb) bsum[threadIdx.x] = s[threadIdx.x] - v;
}

// finalize rp; seed cursor4[d*8+b] = start offset of bucket b within d's segment
__global__ void k_scanC(int* __restrict__ rp, const int* __restrict__ bsum,
                        const int* __restrict__ cnt4, int* __restrict__ cursor4,
                        int n, int E) {
    int i = blockIdx.x * 256 + threadIdx.x;
    if (i < n) {
        int r = rp[i] + bsum[blockIdx.x];
        rp[i] = r;
        int run = r;
        #pragma unroll
        for (int b = 0; b < 8; ++b) {
            cursor4[(i << 3) + b] = run;
            run += cnt4[(i << 3) + b];
        }
    }
    if (i == 0) rp[n] = E;
}

// -------- fused scatter + layer-1 GEMM (independent work overlapped in one grid) ----
// blocks 0..2047: XCD-partitioned scatter (atomic-write-through bound)
// blocks 2048.. : mm1 (x@W1, dis-folded, bf16 out) -- W read DIRECT from global
// [R13 lesson: NO LDS here -- a static 32KB tile was charged to the scatter blocks
//  too, capping residency at 5 blk/CU and throttling the atomic half. W1 (32KB,
//  read-only, hit by all mm blocks) stays L2-hot; wv loads pipeline like LDS did]
__global__ __launch_bounds__(256) void k_scat_mm(const int* __restrict__ src,
                                                 const int* __restrict__ dst,
                                                 int* __restrict__ cursor4,
                                                 uint* __restrict__ epack, int E, int n,
                                                 const float* __restrict__ x,
                                                 const float* __restrict__ W1,
                                                 const float* __restrict__ dis,
                                                 u16* __restrict__ hw) {
    if (blockIdx.x < 2048) {
        const int part = blockIdx.x & 7;
        const int nblk = 2048 >> 3;
        const int bser = blockIdx.x >> 3;
        const int lo = (int)(((long long)part * n) >> 3);
        const int hi = (part == 7) ? n : (int)(((long long)(part + 1) * n) >> 3);
        for (int e = bser * 256 + threadIdx.x; e < E; e += nblk * 256) {
            int d = dst[e];
            if (d >= lo && d < hi) {
                int s = src[e];
                int b = min(s >> BSH, 7);
                int pos = atomicAdd(&cursor4[(d << 3) + b], 1);
                epack[pos] = (uint)s;
            }
        }
    } else {
        const int tx = threadIdx.x & 15;
        const int ty = threadIdx.x >> 4;
        const int node0 = (int)(blockIdx.x - 2048) * 64;
        const float* xr[4];
        #pragma unroll
        for (int i = 0; i < 4; ++i) {
            int gn = node0 + ty * 4 + i;
            xr[i] = x + (long long)min(gn, n - 1) * 128;
        }
        float acc[4][4];
        #pragma unroll
        for (int i = 0; i < 4; ++i)
            #pragma unroll
            for (int j = 0; j < 4; ++j) acc[i][j] = 0.f;

        for (int k0 = 0; k0 < 128; k0 += 4) {
            float4 av[4];
            #pragma unroll
            for (int i = 0; i < 4; ++i)
                av[i] = *((const float4*)&xr[i][k0]);
            #pragma unroll
            for (int kk = 0; kk < 4; ++kk) {
                float4 wv = *((const float4*)&W1[(k0 + kk) * 64 + tx * 4]);
                float a0 = (&av[0].x)[kk];
                float a1 = (&av[1].x)[kk];
                float a2 = (&av[2].x)[kk];
                float a3 = (&av[3].x)[kk];
                acc[0][0] = fmaf(a0, wv.x, acc[0][0]); acc[0][1] = fmaf(a0, wv.y, acc[0][1]);
                acc[0][2] = fmaf(a0, wv.z, acc[0][2]); acc[0][3] = fmaf(a0, wv.w, acc[0][3]);
                acc[1][0] = fmaf(a1, wv.x, acc[1][0]); acc[1][1] = fmaf(a1, wv.y, acc[1][1]);
                acc[1][2] = fmaf(a1, wv.z, acc[1][2]); acc[1][3] = fmaf(a1, wv.w, acc[1][3]);
                acc[2][0] = fmaf(a2, wv.x, acc[2][0]); acc[2][1] = fmaf(a2, wv.y, acc[2][1]);
                acc[2][2] = fmaf(a2, wv.z, acc[2][2]); acc[2][3] = fmaf(a2, wv.w, acc[2][3]);
                acc[3][0] = fmaf(a3, wv.x, acc[3][0]); acc[3][1] = fmaf(a3, wv.y, acc[3][1]);
                acc[3][2] = fmaf(a3, wv.z, acc[3][2]); acc[3][3] = fmaf(a3, wv.w, acc[3][3]);
            }
        }
        #pragma unroll
        for (int i = 0; i < 4; ++i) {
            int gn = node0 + ty * 4 + i;
            if (gn < n) {
                float dv = dis[gn];
                ushort4 o;
                o.x = f2b(acc[i][0] * dv); o.y = f2b(acc[i][1] * dv);
                o.z = f2b(acc[i][2] * dv); o.w = f2b(acc[i][3] * dv);
                ((ushort4*)(hw + (long long)gn * 64))[tx] = o;
            }
        }
    }
}

// ---- tiled GEMM (+fused BN-apply+LeakyReLU on input) + dis-fold output (layers 2/3) --
template <int FIN, int FOUT, bool BN>
__global__ __launch_bounds__(256) void k_mm(const float* __restrict__ h,
                                            const float* __restrict__ W,
                                            const float* __restrict__ dis,
                                            const float* __restrict__ stats,
                                            const float* __restrict__ gma,
                                            const float* __restrict__ bta,
                                            u16* __restrict__ hw, int n) {
    constexpr int FX  = FOUT / 4;
    constexpr int TY  = 256 / FX;
    constexpr int NT  = TY * 4;
    constexpr int LDA = FIN + ((FOUT == 64) ? 2 : 1);
    __shared__ float sA[NT * LDA];
    __shared__ float sW[FIN * FOUT];
    __shared__ float sSc[FIN], sSh[FIN];

    if (BN && threadIdx.x < FIN) {
        int f = threadIdx.x;
        float s = 0.f, q = 0.f;
        #pragma unroll 8
        for (int r = 0; r < SREP; ++r) {
            s += stats[(r << 7) + f];
            q += stats[(r << 7) + 64 + f];
        }
        float inv_n = 1.0f / (float)n;
        float m = s * inv_n;
        float var = fmaxf(q * inv_n - m * m, 0.f);
        float sc = rsqrtf(var + 1e-5f) * gma[f];
        sSc[f] = sc;
        sSh[f] = bta[f] - m * sc;
    }
    for (int i = threadIdx.x; i < FIN * FOUT / 4; i += 256)
        ((float4*)sW)[i] = ((const float4*)W)[i];
    if (BN) __syncthreads();

    const int node0 = blockIdx.x * NT;
    constexpr int LD4 = NT * FIN / 4 / 256;
    #pragma unroll
    for (int i = 0; i < LD4; ++i) {
        int idx4 = i * 256 + threadIdx.x;
        int row = idx4 / (FIN / 4);
        int c4  = idx4 % (FIN / 4);
        int gn  = node0 + row;
        float4 v = make_float4(0.f, 0.f, 0.f, 0.f);
        if (gn < n) v = ((const float4*)(h + (long long)gn * FIN))[c4];
        if (BN) {
            int f = c4 * 4;
            float t;
            t = fmaf(v.x, sSc[f + 0], sSh[f + 0]); v.x = t > 0.f ? t : 0.1f * t;
            t = fmaf(v.y, sSc[f + 1], sSh[f + 1]); v.y = t > 0.f ? t : 0.1f * t;
            t = fmaf(v.z, sSc[f + 2], sSh[f + 2]); v.z = t > 0.f ? t : 0.1f * t;
            t = fmaf(v.w, sSc[f + 3], sSh[f + 3]); v.w = t > 0.f ? t : 0.1f * t;
        }
        float* p = &sA[row * LDA + c4 * 4];
        p[0] = v.x; p[1] = v.y; p[2] = v.z; p[3] = v.w;
    }
    __syncthreads();

    const int tx = threadIdx.x % FX;
    const int ty = threadIdx.x / FX;
    float acc[4][4];
    #pragma unroll
    for (int i = 0; i < 4; ++i)
        #pragma unroll
        for (int j = 0; j < 4; ++j) acc[i][j] = 0.f;

    #pragma unroll 8
    for (int k = 0; k < FIN; ++k) {
        float4 wv = *((const float4*)&sW[k * FOUT + tx * 4]);
        float a0 = sA[(ty * 4 + 0) * LDA + k];
        float a1 = sA[(ty * 4 + 1) * LDA + k];
        float a2 = sA[(ty * 4 + 2) * LDA + k];
        float a3 = sA[(ty * 4 + 3) * LDA + k];
        acc[0][0] = fmaf(a0, wv.x, acc[0][0]); acc[0][1] = fmaf(a0, wv.y, acc[0][1]);
        acc[0][2] = fmaf(a0, wv.z, acc[0][2]); acc[0][3] = fmaf(a0, wv.w, acc[0][3]);
        acc[1][0] = fmaf(a1, wv.x, acc[1][0]); acc[1][1] = fmaf(a1, wv.y, acc[1][1]);
        acc[1][2] = fmaf(a1, wv.z, acc[1][2]); acc[1][3] = fmaf(a1, wv.w, acc[1][3]);
        acc[2][0] = fmaf(a2, wv.x, acc[2][0]); acc[2][1] = fmaf(a2, wv.y, acc[2][1]);
        acc[2][2] = fmaf(a2, wv.z, acc[2][2]); acc[2][3] = fmaf(a2, wv.w, acc[2][3]);
        acc[3][0] = fmaf(a3, wv.x, acc[3][0]); acc[3][1] = fmaf(a3, wv.y, acc[3][1]);
        acc[3][2] = fmaf(a3, wv.z, acc[3][2]); acc[3][3] = fmaf(a3, wv.w, acc[3][3]);
    }

    #pragma unroll
    for (int i = 0; i < 4; ++i) {
        int gn = node0 + ty * 4 + i;
        if (gn < n) {
            float dv = dis[gn];
            ushort4 o;
            o.x = f2b(acc[i][0] * dv); o.y = f2b(acc[i][1] * dv);
            o.z = f2b(acc[i][2] * dv); o.w = f2b(acc[i][3] * dv);
            ((ushort4*)(hw + (long long)gn * FOUT))[tx] = o;
        }
    }
}

// ------- transposed bucketed aggregation: each 8-lane group walks T nodes'
// current-bucket segments simultaneously -> T independent gather chains per trip
// (bucket-lockstep L2 locality preserved; register accumulation; no LDS atomics)
// [R9: no software tile prefetch. R4/R5 invariant: MSHR x L3-latency floor]
template <int FOUT, int T>
__global__ __launch_bounds__(256) void k_aggt(const u16* __restrict__ hwb,
                                              const uint* __restrict__ epack,
                                              const int* __restrict__ rp,
                                              const int* __restrict__ cursor4,
                                              const float* __restrict__ dis,
                                              const float* __restrict__ bias,
                                              float* __restrict__ y,
                                              float* __restrict__ stats,
                                              int n, int nbuck) {
    constexpr int LPN = FOUT / 8;          // lanes per node (uint4 = 8 bf16)
    constexpr int GPB = 256 / LPN;         // groups per block
    constexpr int NPB = GPB * T;           // nodes per block
    constexpr int RS  = FOUT / 8;          // row stride in uint4
    __shared__ float ssum[FOUT], ssq[FOUT];
    for (int i = threadIdx.x; i < FOUT; i += 256) { ssum[i] = 0.f; ssq[i] = 0.f; }
    __syncthreads();
    const int grp = threadIdx.x / LPN;
    const int fq  = threadIdx.x % LPN;
    const uint4* hw4 = (const uint4*)hwb;

    int nd[T], jp[T];
    float acc[T][8];
    #pragma unroll
    for (int t = 0; t < T; ++t) {
        nd[t] = blockIdx.x * NPB + grp * T + t;
        jp[t] = (nd[t] < n) ? rp[nd[t]] : 0;
        #pragma unroll
        for (int i = 0; i < 8; ++i) acc[t][i] = 0.f;
    }

    for (int b = 0; b < nbuck; ++b) {
        int je[T];
        #pragma unroll
        for (int t = 0; t < T; ++t)
            je[t] = (nd[t] < n) ? cursor4[(nd[t] << 3) + b] : 0;
        bool more = (jp[0] < je[0]);
        #pragma unroll
        for (int t = 1; t < T; ++t) more |= (jp[t] < je[t]);
        while (more) {
            more = false;
            uint idx[T];
            bool act[T];
            #pragma unroll
            for (int t = 0; t < T; ++t) {             // T independent index loads
                act[t] = jp[t] < je[t];
                idx[t] = epack[act[t] ? jp[t] : 0];
            }
            uint4 q[T];
            #pragma unroll
            for (int t = 0; t < T; ++t) {             // T independent row gathers
                int row = act[t] ? (int)idx[t] : min(nd[t], n - 1);  // dummy = own row (L1-hot)
                q[t] = hw4[(long long)row * RS + fq];
            }
            #pragma unroll
            for (int t = 0; t < T; ++t) {
                if (act[t]) {
                    add8(q[t], acc[t]);
                    ++jp[t];
                    more |= (jp[t] < je[t]);
                }
            }
        }
    }

    // epilogue: + self term, * dis, + bias, write y, BN stats
    float lsum[8] = {0,0,0,0,0,0,0,0}, lsq[8] = {0,0,0,0,0,0,0,0};
    float b8[8];
    #pragma unroll
    for (int i = 0; i < 8; ++i) b8[i] = bias[fq * 8 + i];
    #pragma unroll
    for (int t = 0; t < T; ++t) {
        int node = nd[t];
        if (node < n) {
            uint4 qs = hw4[(long long)node * RS + fq];
            add8(qs, acc[t]);                  // + hw'[d] (self term)
            float dv = dis[node];
            #pragma unroll
            for (int i = 0; i < 8; ++i) acc[t][i] = fmaf(dv, acc[t][i], b8[i]);
            float4* y4 = (float4*)y;
            long long o = (long long)node * (FOUT / 4) + fq * 2;
            y4[o]     = make_float4(acc[t][0], acc[t][1], acc[t][2], acc[t][3]);
            y4[o + 1] = make_float4(acc[t][4], acc[t][5], acc[t][6], acc[t][7]);
            #pragma unroll
            for (int i = 0; i < 8; ++i) {
                lsum[i] += acc[t][i];
                lsq[i] = fmaf(acc[t][i], acc[t][i], lsq[i]);
            }
        }
    }
    #pragma unroll
    for (int i = 0; i < 8; ++i) {
        atomicAdd(&ssum[fq * 8 + i], lsum[i]);
        atomicAdd(&ssq[fq * 8 + i], lsq[i]);
    }
    __syncthreads();
    float* st = stats + ((blockIdx.x & (SREP - 1)) << 7);
    for (int i = threadIdx.x; i < FOUT; i += 256) {
        atomicAdd(&st[i], ssum[i]);
        atomicAdd(&st[64 + i], ssq[i]);
    }
}

// ------- full-range CSR aggregation, flat 8-deep (layer 3: 3.2MB table L2-fits) ------
template <int FOUT>
__global__ __launch_bounds__(256) void k_agg(const u16* __restrict__ hwb,
                                             const uint* __restrict__ epack,
                                             const int* __restrict__ rp,
                                             const float* __restrict__ dis,
                                             const float* __restrict__ bias,
                                             float* __restrict__ y,
                                             float* __restrict__ stats, int n) {
    constexpr int LPN = FOUT / 8;
    constexpr int NPB = 256 / LPN;
    constexpr int RS  = FOUT / 8;
    __shared__ float ssum[FOUT], ssq[FOUT];
    for (int i = threadIdx.x; i < FOUT; i += 256) { ssum[i] = 0.f; ssq[i] = 0.f; }
    __syncthreads();
    const int local = threadIdx.x / LPN;
    const int fq = threadIdx.x % LPN;
    const uint4* hw4 = (const uint4*)hwb;
    float b8[8];
    #pragma unroll
    for (int i = 0; i < 8; ++i) b8[i] = bias[fq * 8 + i];
    float lsum[8] = {0,0,0,0,0,0,0,0}, lsq[8] = {0,0,0,0,0,0,0,0};

    int node = blockIdx.x * NPB + local;
    if (node < n) {
        int j0 = rp[node], j1 = rp[node + 1];
        float acc[8] = {0,0,0,0,0,0,0,0};
        int j = j0;
        for (; j + 8 <= j1; j += 8) {
            uint s0 = epack[j + 0], s1 = epack[j + 1], s2 = epack[j + 2], s3 = epack[j + 3];
            uint s4 = epack[j + 4], s5 = epack[j + 5], s6 = epack[j + 6], s7 = epack[j + 7];
            uint4 q0 = hw4[(long long)s0 * RS + fq];
            uint4 q1 = hw4[(long long)s1 * RS + fq];
            uint4 q2 = hw4[(long long)s2 * RS + fq];
            uint4 q3 = hw4[(long long)s3 * RS + fq];
            uint4 q4 = hw4[(long long)s4 * RS + fq];
            uint4 q5 = hw4[(long long)s5 * RS + fq];
            uint4 q6 = hw4[(long long)s6 * RS + fq];
            uint4 q7 = hw4[(long long)s7 * RS + fq];
            add8(q0, acc); add8(q1, acc); add8(q2, acc); add8(q3, acc);
            add8(q4, acc); add8(q5, acc); add8(q6, acc); add8(q7, acc);
        }
        for (; j + 2 <= j1; j += 2) {
            uint s0 = epack[j + 0], s1 = epack[j + 1];
            uint4 q0 = hw4[(long long)s0 * RS + fq];
            uint4 q1 = hw4[(long long)s1 * RS + fq];
            add8(q0, acc); add8(q1, acc);
        }
        for (; j < j1; ++j) {
            uint4 q = hw4[(long long)epack[j] * RS + fq];
            add8(q, acc);
        }
        uint4 qs = hw4[(long long)node * RS + fq];
        add8(qs, acc);
        float dv = dis[node];
        #pragma unroll
        for (int i = 0; i < 8; ++i) acc[i] = fmaf(dv, acc[i], b8[i]);
        float4* y4 = (float4*)y;
        long long o = (long long)node * (FOUT / 4) + fq * 2;
        y4[o]     = make_float4(acc[0], acc[1], acc[2], acc[3]);
        y4[o + 1] = make_float4(acc[4], acc[5], acc[6], acc[7]);
        #pragma unroll
        for (int i = 0; i < 8; ++i) {
            lsum[i] += acc[i];
            lsq[i] = fmaf(acc[i], acc[i], lsq[i]);
        }
    }
    #pragma unroll
    for (int i = 0; i < 8; ++i) {
        atomicAdd(&ssum[fq * 8 + i], lsum[i]);
        atomicAdd(&ssq[fq * 8 + i], lsq[i]);
    }
    __syncthreads();
    float* st = stats + ((blockIdx.x & (SREP - 1)) << 7);
    for (int i = threadIdx.x; i < FOUT; i += 256) {
        atomicAdd(&st[i], ssum[i]);
        atomicAdd(&st[64 + i], ssq[i]);
    }
}

// -------- pooling (fused BN-apply+LeakyReLU): 8 blocks per graph (512 blocks,
// R9-verified win vs 64-block launch); partials reduced in k_head ----
__global__ void k_pool_graph(const float* __restrict__ yraw, const int* __restrict__ batch,
                             const float* __restrict__ stats, const float* __restrict__ gma,
                             const float* __restrict__ bta, int n,
                             float* __restrict__ psum, float* __restrict__ pmax,
                             float* __restrict__ pcnt) {
    const int g    = blockIdx.x >> 3;
    const int part = blockIdx.x & 7;
    const int f = threadIdx.x & 15;
    float s = 0.f, q = 0.f;
    #pragma unroll 8
    for (int r = 0; r < SREP; ++r) {
        s += stats[(r << 7) + f];
        q += stats[(r << 7) + 64 + f];
    }
    float inv_n = 1.0f / (float)n;
    float m = s * inv_n;
    float var = fmaxf(q * inv_n - m * m, 0.f);
    float sc = rsqrtf(var + 1e-5f) * gma[f];
    float sh = bta[f] - m * sc;

    __shared__ int s_lo, s_hi;
    if (threadIdx.x == 0) {
        int lo = 0, hi = n;
        while (lo < hi) { int mid = (lo + hi) >> 1; if (batch[mid] < g) lo = mid + 1; else hi = mid; }
        s_lo = lo;
        hi = n;
        while (lo < hi) { int mid = (lo + hi) >> 1; if (batch[mid] < g + 1) lo = mid + 1; else hi = mid; }
        s_hi = lo;
    }
    __syncthreads();
    const int gs = s_lo, len = s_hi - s_lo;
    const int start = gs + (int)(((long long)len * part) >> 3);
    const int end   = gs + (int)(((long long)len * (part + 1)) >> 3);
    float lsum = 0.f, lmax = -3.0e38f;
    for (long long idx = (long long)start * 16 + threadIdx.x; idx < (long long)end * 16; idx += blockDim.x) {
        float t = fmaf(yraw[idx], sc, sh);
        float v = t > 0.f ? t : 0.1f * t;
        lsum += v;
        lmax = fmaxf(lmax, v);
    }
    __shared__ float ss[256], sm[256];
    ss[threadIdx.x] = lsum; sm[threadIdx.x] = lmax;
    __syncthreads();
    for (int off = 128; off >= 16; off >>= 1) {
        if (threadIdx.x < off) {
            ss[threadIdx.x] += ss[threadIdx.x + off];
            sm[threadIdx.x] = fmaxf(sm[threadIdx.x], sm[threadIdx.x + off]);
        }
        __syncthreads();
    }
    if (threadIdx.x < 16) {
        psum[(((g << 3) + part) << 4) + threadIdx.x] = ss[threadIdx.x];
        pmax[(((g << 3) + part) << 4) + threadIdx.x] = sm[threadIdx.x];
    }
    if (threadIdx.x == 0) pcnt[(g << 3) + part] = (float)(end - start);
}

// ---------------- head (reduces the 8 pooling partials per graph) ----------------
__global__ void k_head(const float* __restrict__ psum, const float* __restrict__ pmax,
                       const float* __restrict__ pcnt,
                       const float* __restrict__ attn_w, const float* __restrict__ attn_b,
                       const float* __restrict__ fc1_w, const float* __restrict__ fc1_b,
                       const float* __restrict__ fc2_w, const float* __restrict__ fc2_b,
                       const float* __restrict__ out_w, const float* __restrict__ out_b,
                       float* __restrict__ out) {
    int g = threadIdx.x;
    if (g >= GG) return;
    float xs[16], xm[16], xx[16];
    float c = 0.f;
    for (int p = 0; p < 8; ++p) c += pcnt[(g << 3) + p];
    c = fmaxf(c, 1.0f);
    for (int f = 0; f < 16; ++f) { xs[f] = 0.f; xx[f] = -3.0e38f; }
    for (int p = 0; p < 8; ++p) {
        for (int f = 0; f < 16; ++f) {
            xs[f] += psum[(((g << 3) + p) << 4) + f];
            xx[f] = fmaxf(xx[f], pmax[(((g << 3) + p) << 4) + f]);
        }
    }
    for (int f = 0; f < 16; ++f) xm[f] = xs[f] / c;
    float lg[3];
    for (int cI = 0; cI < 3; ++cI) {
        float a = attn_b[cI];
        for (int f = 0; f < 16; ++f) {
            a += xm[f] * attn_w[f * 3 + cI];
            a += xx[f] * attn_w[(16 + f) * 3 + cI];
            a += xs[f] * attn_w[(32 + f) * 3 + cI];
        }
        lg[cI] = a;
    }
    float mx = fmaxf(lg[0], fmaxf(lg[1], lg[2]));
    float e0 = expf(lg[0] - mx), e1 = expf(lg[1] - mx), e2 = expf(lg[2] - mx);
    float inv = 1.0f / (e0 + e1 + e2);
    float a0 = e0 * inv, a1 = e1 * inv, a2 = e2 * inv;
    float xg[16];
    for (int f = 0; f < 16; ++f) xg[f] = a0 * xm[f] + a1 * xx[f] + a2 * xs[f];
    float t1[16];
    for (int j = 0; j < 16; ++j) {
        float a = fc1_b[j];
        for (int k = 0; k < 16; ++k) a += xg[k] * fc1_w[k * 16 + j];
        t1[j] = a > 0.f ? a : 0.1f * a;
    }
    float t2[8];
    for (int j = 0; j < 8; ++j) {
        float a = fc2_b[j];
        for (int k = 0; k < 16; ++k) a += t1[k] * fc2_w[k * 8 + j];
        t2[j] = a > 0.f ? a : 0.1f * a;
    }
    float o = out_b[0];
    for (int k = 0; k < 8; ++k) o += t2[k] * out_w[k];
    o = 1.0f / (1.0f + expf(-o));
    out[g] = o;
}

extern "C" void kernel_launch(void* const* d_in, const int* in_sizes, int n_in,
                              void* d_out, int out_size, void* d_ws, size_t ws_size,
                              hipStream_t stream) {
    const float* x      = (const float*)d_in[0];
    const float* W1     = (const float*)d_in[1];  const float* b1   = (const float*)d_in[2];
    const float* W2     = (const float*)d_in[3];  const float* b2   = (const float*)d_in[4];
    const float* W3     = (const float*)d_in[5];  const float* b3   = (const float*)d_in[6];
    const float* g1     = (const float*)d_in[7];  const float* be1  = (const float*)d_in[8];
    const float* g2     = (const float*)d_in[9];  const float* be2  = (const float*)d_in[10];
    const float* g3     = (const float*)d_in[11]; const float* be3  = (const float*)d_in[12];
    const float* attn_w = (const float*)d_in[13]; const float* attn_b = (const float*)d_in[14];
    const float* fc1_w  = (const float*)d_in[15]; const float* fc1_b  = (const float*)d_in[16];
    const float* fc2_w  = (const float*)d_in[17]; const float* fc2_b  = (const float*)d_in[18];
    const float* out_w  = (const float*)d_in[19]; const float* out_b  = (const float*)d_in[20];
    const int* edge_index = (const int*)d_in[21];
    const int* batch      = (const int*)d_in[22];

    const int N = in_sizes[0] / 128;
    const int E = in_sizes[21] / 2;
    const int* srcp = edge_index;
    const int* dstp = edge_index + E;
    const int nb = (N + 255) / 256;
    const int NBUCK = min((N + (1 << BSH) - 1) >> BSH, 8);

    char* ws = (char*)d_ws;
    float* dis    = (float*)(ws);                 // N f32
    int*   rp     = (int*)(ws + 0x100000);        // N+1 int
    int*   bsum   = (int*)(ws + 0x180000);        // <=512 int (2KB)
    float* stats1 = (float*)(ws + 0x180800);      // SREP*128 f32 = 16KB per layer
    float* stats2 = (float*)(ws + 0x184800);
    float* stats3 = (float*)(ws + 0x188800);
    float* psum   = (float*)(ws + 0x80000);       // 64*8*16 f32 = 32KB
    float* pmax   = psum + GG * 8 * 16;           // 32KB
    float* pcnt   = pmax + GG * 8 * 16;           // 2KB
    int*   cnt4    = (int*)(ws + 0x190000);       // 8N int
    int*   cursor4 = cnt4 + (size_t)8 * N;        // 8N int
    uint*  epack   = (uint*)(cursor4 + (size_t)8 * N);   // E uint
    float* buf1    = (float*)((char*)epack + (((size_t)E * 4 + 255) & ~(size_t)255));
    u16*   hwb     = (u16*)(buf1 + (size_t)N * 64);

    // ---- bucketed CSR build (atomic kernels XCD-partitioned) ----
    hipMemsetAsync(cnt4, 0, (size_t)N * 32, stream);
    k_hist<<<2048, 256, 0, stream>>>(srcp, dstp, cnt4, E, N);
    k_scanA<<<nb, 256, 0, stream>>>(cnt4, rp, bsum, dis, N);   // fused degree+dis+scan
    k_scanB<<<1, 512, 0, stream>>>(bsum, nb);
    k_scanC<<<nb, 256, 0, stream>>>(rp, bsum, cnt4, cursor4, N, E);
    hipMemsetAsync(stats1, 0, 3 * SREP * 512, stream);

    // ---- fused: scatter (atomic-bound) overlapped with layer-1 GEMM (BW/FLOP) ----
    k_scat_mm<<<2048 + (N + 63) / 64, 256, 0, stream>>>(
        srcp, dstp, cursor4, epack, E, N, x, W1, dis, hwb);
    k_aggt<64, 4><<<(N + 127) / 128, 256, 0, stream>>>(
        hwb, epack, rp, cursor4, dis, b1, buf1, stats1, N, NBUCK);

    // ---- layer 2 (BN1+lrelu fused into staging); transposed bucketed agg ----
    k_mm<64, 32, true><<<(N + 127) / 128, 256, 0, stream>>>(
        buf1, W2, dis, stats1, g1, be1, hwb, N);
    k_aggt<32, 4><<<(N + 255) / 256, 256, 0, stream>>>(
        hwb, epack, rp, cursor4, dis, b2, buf1, stats2, N, NBUCK);

    // ---- layer 3 (BN2+lrelu fused); table fits L2, flat 8-deep agg ----
    k_mm<32, 16, true><<<(N + 255) / 256, 256, 0, stream>>>(
        buf1, W3, dis, stats2, g2, be2, hwb, N);
    k_agg<16><<<(N + 127) / 128, 256, 0, stream>>>(hwb, epack, rp, dis, b3, buf1, stats3, N);

    // ---- pooling (BN3+lrelu fused, 8 blocks/graph) + head (reduces partials) ----
    k_pool_graph<<<GG * 8, 256, 0, stream>>>(buf1, batch, stats3, g3, be3, N, psum, pmax, pcnt);
    k_head<<<1, 64, 0, stream>>>(psum, pmax, pcnt, attn_w, attn_b,
                                 fc1_w, fc1_b, fc2_w, fc2_b, out_w, out_b,
                                 (float*)d_out);
}

// Round 15
// 511.588 us; speedup vs baseline: 1.0411x; 1.0411x over previous
//
#include <hip/hip_runtime.h>

#define GG 64    // num_graphs (fixed by problem)
#define SREP 32  // BN-stats replicas: spreads lane-atomics over 32x cache lines
#define BSH 14   // source-bucket shift: 16384-node tiles (2MB of 128B rows) -> L2-resident
typedef unsigned long long ull;
typedef unsigned short u16;
typedef unsigned int uint;

__device__ __forceinline__ u16 f2b(float x) {          // fp32 -> bf16 (RN-even)
    unsigned u = __float_as_uint(x);
    return (u16)((u + 0x7FFFu + ((u >> 16) & 1u)) >> 16);
}

// unpack uint4 (8 bf16) and ADD into acc[8]
__device__ __forceinline__ void add8(const uint4 q, float* acc) {
    acc[0] += __uint_as_float(q.x << 16);
    acc[1] += __uint_as_float(q.x & 0xFFFF0000u);
    acc[2] += __uint_as_float(q.y << 16);
    acc[3] += __uint_as_float(q.y & 0xFFFF0000u);
    acc[4] += __uint_as_float(q.z << 16);
    acc[5] += __uint_as_float(q.z & 0xFFFF0000u);
    acc[6] += __uint_as_float(q.w << 16);
    acc[7] += __uint_as_float(q.w & 0xFFFF0000u);
}

// ---------------- CSR build (bucketed by source tile) ----------------
// XCD-partitioned hist (fire-and-forget atomics; partition keeps lines L2-exclusive).
// [R11 lesson: fetch-add atomics write through (~60MB/1.6M RMWs) regardless of
//  partitioning; the 8x dst re-read here is L3-served and ~free (R6/R8/R11 evidence)]
__global__ __launch_bounds__(256) void k_hist(const int* __restrict__ src,
                                              const int* __restrict__ dst,
                                              int* __restrict__ cnt4, int E, int n) {
    const int part = blockIdx.x & 7;
    const int nblk = gridDim.x >> 3;
    const int bser = blockIdx.x >> 3;
    const int lo = (int)(((long long)part * n) >> 3);
    const int hi = (part == 7) ? n : (int)(((long long)(part + 1) * n) >> 3);
    for (int e = bser * 256 + threadIdx.x; e < E; e += nblk * 256) {
        int d = dst[e];
        if (d >= lo && d < hi) {
            int b = min(src[e] >> BSH, 7);
            atomicAdd(&cnt4[(d << 3) + b], 1);
        }
    }
}

// fused: degree+dis from cnt4, then intra-block exclusive scan (saves the k_sum4 pass)
__global__ void k_scanA(const int* __restrict__ cnt4, int* __restrict__ rp,
                        int* __restrict__ bsum, float* __restrict__ dis, int n) {
    __shared__ int s[256];
    int i = blockIdx.x * 256 + threadIdx.x;
    int v = 0;
    if (i < n) {
        #pragma unroll
        for (int b = 0; b < 8; ++b) v += cnt4[(i << 3) + b];
        dis[i] = rsqrtf((float)v + 1.0f);
    }
    s[threadIdx.x] = v;
    __syncthreads();
    for (int off = 1; off < 256; off <<= 1) {
        int t = (threadIdx.x >= off) ? s[threadIdx.x - off] : 0;
        __syncthreads();
        s[threadIdx.x] += t;
        __syncthreads();
    }
    if (i < n) rp[i] = s[threadIdx.x] - v;
    if (threadIdx.x == 255) bsum[blockIdx.x] = s[255];
}

__global__ void k_scanB(int* __restrict__ bsum, int nb) {
    __shared__ int s[512];
    int v = (threadIdx.x < nb) ? bsum[threadIdx.x] : 0;
    s[threadIdx.x] = v;
    __syncthreads();
    for (int off = 1; off < 512; off <<= 1) {
        int t = (threadIdx.x >= off) ? s[threadIdx.x - off] : 0;
        __syncthreads();
        s[threadIdx.x] += t;
        __syncthreads();
    }
    if (threadIdx.x < nb) bsum[threadIdx.x] = s[threadIdx.x] - v;
}

// finalize rp; seed cursor4[d*8+b] = start offset of bucket b within d's segment
__global__ void k_scanC(int* __restrict__ rp, const int* __restrict__ bsum,
                        const int* __restrict__ cnt4, int* __restrict__ cursor4,
                        int n, int E) {
    int i = blockIdx.x * 256 + threadIdx.x;
    if (i < n) {
        int r = rp[i] + bsum[blockIdx.x];
        rp[i] = r;
        int run = r;
        #pragma unroll
        for (int b = 0; b < 8; ++b) {
            cursor4[(i << 3) + b] = run;
            run += cnt4[(i << 3) + b];
        }
    }
    if (i == 0) rp[n] = E;
}

// -------- fused scatter + layer-1 GEMM (independent work overlapped in one grid) ----
// blocks 0..2047: XCD-partitioned scatter (atomic-write-through bound)
// blocks 2048.. : mm1 (x@W1, dis-folded, bf16 out) with W1 in a 32KB LDS tile.
// [R14 lesson: the 32KB LDS charged to ALL blocks (incl. scatter) caps residency at
//  5 blk/CU -- and that's GOOD: it throttles concurrent RMWs, so cursor4 write-through
//  merges better in L2 (82 vs 96MB) and the atomic fabric queue stays shorter.
//  Removing the LDS raised occupancy to 68% but cost +19us. Keep the throttle.]
__global__ __launch_bounds__(256) void k_scat_mm(const int* __restrict__ src,
                                                 const int* __restrict__ dst,
                                                 int* __restrict__ cursor4,
                                                 uint* __restrict__ epack, int E, int n,
                                                 const float* __restrict__ x,
                                                 const float* __restrict__ W1,
                                                 const float* __restrict__ dis,
                                                 u16* __restrict__ hw) {
    __shared__ float sW[128 * 64];
    if (blockIdx.x < 2048) {
        const int part = blockIdx.x & 7;
        const int nblk = 2048 >> 3;
        const int bser = blockIdx.x >> 3;
        const int lo = (int)(((long long)part * n) >> 3);
        const int hi = (part == 7) ? n : (int)(((long long)(part + 1) * n) >> 3);
        for (int e = bser * 256 + threadIdx.x; e < E; e += nblk * 256) {
            int d = dst[e];
            if (d >= lo && d < hi) {
                int s = src[e];
                int b = min(s >> BSH, 7);
                int pos = atomicAdd(&cursor4[(d << 3) + b], 1);
                epack[pos] = (uint)s;
            }
        }
    } else {
        for (int i = threadIdx.x; i < 128 * 64 / 4; i += 256)
            ((float4*)sW)[i] = ((const float4*)W1)[i];
        __syncthreads();
        const int tx = threadIdx.x & 15;
        const int ty = threadIdx.x >> 4;
        const int node0 = (int)(blockIdx.x - 2048) * 64;
        const float* xr[4];
        #pragma unroll
        for (int i = 0; i < 4; ++i) {
            int gn = node0 + ty * 4 + i;
            xr[i] = x + (long long)min(gn, n - 1) * 128;
        }
        float acc[4][4];
        #pragma unroll
        for (int i = 0; i < 4; ++i)
            #pragma unroll
            for (int j = 0; j < 4; ++j) acc[i][j] = 0.f;

        for (int k0 = 0; k0 < 128; k0 += 4) {
            float4 av[4];
            #pragma unroll
            for (int i = 0; i < 4; ++i)
                av[i] = *((const float4*)&xr[i][k0]);
            #pragma unroll
            for (int kk = 0; kk < 4; ++kk) {
                float4 wv = *((const float4*)&sW[(k0 + kk) * 64 + tx * 4]);
                float a0 = (&av[0].x)[kk];
                float a1 = (&av[1].x)[kk];
                float a2 = (&av[2].x)[kk];
                float a3 = (&av[3].x)[kk];
                acc[0][0] = fmaf(a0, wv.x, acc[0][0]); acc[0][1] = fmaf(a0, wv.y, acc[0][1]);
                acc[0][2] = fmaf(a0, wv.z, acc[0][2]); acc[0][3] = fmaf(a0, wv.w, acc[0][3]);
                acc[1][0] = fmaf(a1, wv.x, acc[1][0]); acc[1][1] = fmaf(a1, wv.y, acc[1][1]);
                acc[1][2] = fmaf(a1, wv.z, acc[1][2]); acc[1][3] = fmaf(a1, wv.w, acc[1][3]);
                acc[2][0] = fmaf(a2, wv.x, acc[2][0]); acc[2][1] = fmaf(a2, wv.y, acc[2][1]);
                acc[2][2] = fmaf(a2, wv.z, acc[2][2]); acc[2][3] = fmaf(a2, wv.w, acc[2][3]);
                acc[3][0] = fmaf(a3, wv.x, acc[3][0]); acc[3][1] = fmaf(a3, wv.y, acc[3][1]);
                acc[3][2] = fmaf(a3, wv.z, acc[3][2]); acc[3][3] = fmaf(a3, wv.w, acc[3][3]);
            }
        }
        #pragma unroll
        for (int i = 0; i < 4; ++i) {
            int gn = node0 + ty * 4 + i;
            if (gn < n) {
                float dv = dis[gn];
                ushort4 o;
                o.x = f2b(acc[i][0] * dv); o.y = f2b(acc[i][1] * dv);
                o.z = f2b(acc[i][2] * dv); o.w = f2b(acc[i][3] * dv);
                ((ushort4*)(hw + (long long)gn * 64))[tx] = o;
            }
        }
    }
}

// ---- tiled GEMM (+fused BN-apply+LeakyReLU on input) + dis-fold output (layers 2/3) --
template <int FIN, int FOUT, bool BN>
__global__ __launch_bounds__(256) void k_mm(const float* __restrict__ h,
                                            const float* __restrict__ W,
                                            const float* __restrict__ dis,
                                            const float* __restrict__ stats,
                                            const float* __restrict__ gma,
                                            const float* __restrict__ bta,
                                            u16* __restrict__ hw, int n) {
    constexpr int FX  = FOUT / 4;
    constexpr int TY  = 256 / FX;
    constexpr int NT  = TY * 4;
    constexpr int LDA = FIN + ((FOUT == 64) ? 2 : 1);
    __shared__ float sA[NT * LDA];
    __shared__ float sW[FIN * FOUT];
    __shared__ float sSc[FIN], sSh[FIN];

    if (BN && threadIdx.x < FIN) {
        int f = threadIdx.x;
        float s = 0.f, q = 0.f;
        #pragma unroll 8
        for (int r = 0; r < SREP; ++r) {
            s += stats[(r << 7) + f];
            q += stats[(r << 7) + 64 + f];
        }
        float inv_n = 1.0f / (float)n;
        float m = s * inv_n;
        float var = fmaxf(q * inv_n - m * m, 0.f);
        float sc = rsqrtf(var + 1e-5f) * gma[f];
        sSc[f] = sc;
        sSh[f] = bta[f] - m * sc;
    }
    for (int i = threadIdx.x; i < FIN * FOUT / 4; i += 256)
        ((float4*)sW)[i] = ((const float4*)W)[i];
    if (BN) __syncthreads();

    const int node0 = blockIdx.x * NT;
    constexpr int LD4 = NT * FIN / 4 / 256;
    #pragma unroll
    for (int i = 0; i < LD4; ++i) {
        int idx4 = i * 256 + threadIdx.x;
        int row = idx4 / (FIN / 4);
        int c4  = idx4 % (FIN / 4);
        int gn  = node0 + row;
        float4 v = make_float4(0.f, 0.f, 0.f, 0.f);
        if (gn < n) v = ((const float4*)(h + (long long)gn * FIN))[c4];
        if (BN) {
            int f = c4 * 4;
            float t;
            t = fmaf(v.x, sSc[f + 0], sSh[f + 0]); v.x = t > 0.f ? t : 0.1f * t;
            t = fmaf(v.y, sSc[f + 1], sSh[f + 1]); v.y = t > 0.f ? t : 0.1f * t;
            t = fmaf(v.z, sSc[f + 2], sSh[f + 2]); v.z = t > 0.f ? t : 0.1f * t;
            t = fmaf(v.w, sSc[f + 3], sSh[f + 3]); v.w = t > 0.f ? t : 0.1f * t;
        }
        float* p = &sA[row * LDA + c4 * 4];
        p[0] = v.x; p[1] = v.y; p[2] = v.z; p[3] = v.w;
    }
    __syncthreads();

    const int tx = threadIdx.x % FX;
    const int ty = threadIdx.x / FX;
    float acc[4][4];
    #pragma unroll
    for (int i = 0; i < 4; ++i)
        #pragma unroll
        for (int j = 0; j < 4; ++j) acc[i][j] = 0.f;

    #pragma unroll 8
    for (int k = 0; k < FIN; ++k) {
        float4 wv = *((const float4*)&sW[k * FOUT + tx * 4]);
        float a0 = sA[(ty * 4 + 0) * LDA + k];
        float a1 = sA[(ty * 4 + 1) * LDA + k];
        float a2 = sA[(ty * 4 + 2) * LDA + k];
        float a3 = sA[(ty * 4 + 3) * LDA + k];
        acc[0][0] = fmaf(a0, wv.x, acc[0][0]); acc[0][1] = fmaf(a0, wv.y, acc[0][1]);
        acc[0][2] = fmaf(a0, wv.z, acc[0][2]); acc[0][3] = fmaf(a0, wv.w, acc[0][3]);
        acc[1][0] = fmaf(a1, wv.x, acc[1][0]); acc[1][1] = fmaf(a1, wv.y, acc[1][1]);
        acc[1][2] = fmaf(a1, wv.z, acc[1][2]); acc[1][3] = fmaf(a1, wv.w, acc[1][3]);
        acc[2][0] = fmaf(a2, wv.x, acc[2][0]); acc[2][1] = fmaf(a2, wv.y, acc[2][1]);
        acc[2][2] = fmaf(a2, wv.z, acc[2][2]); acc[2][3] = fmaf(a2, wv.w, acc[2][3]);
        acc[3][0] = fmaf(a3, wv.x, acc[3][0]); acc[3][1] = fmaf(a3, wv.y, acc[3][1]);
        acc[3][2] = fmaf(a3, wv.z, acc[3][2]); acc[3][3] = fmaf(a3, wv.w, acc[3][3]);
    }

    #pragma unroll
    for (int i = 0; i < 4; ++i) {
        int gn = node0 + ty * 4 + i;
        if (gn < n) {
            float dv = dis[gn];
            ushort4 o;
            o.x = f2b(acc[i][0] * dv); o.y = f2b(acc[i][1] * dv);
            o.z = f2b(acc[i][2] * dv); o.w = f2b(acc[i][3] * dv);
            ((ushort4*)(hw + (long long)gn * FOUT))[tx] = o;
        }
    }
}

// ------- transposed bucketed aggregation: each 8-lane group walks T nodes'
// current-bucket segments simultaneously -> T independent gather chains per trip
// (bucket-lockstep L2 locality preserved; register accumulation; no LDS atomics)
// [R9: no software tile prefetch. R4/R5 invariant: MSHR x L3-latency floor]
template <int FOUT, int T>
__global__ __launch_bounds__(256) void k_aggt(const u16* __restrict__ hwb,
                                              const uint* __restrict__ epack,
                                              const int* __restrict__ rp,
                                              const int* __restrict__ cursor4,
                                              const float* __restrict__ dis,
                                              const float* __restrict__ bias,
                                              float* __restrict__ y,
                                              float* __restrict__ stats,
                                              int n, int nbuck) {
    constexpr int LPN = FOUT / 8;          // lanes per node (uint4 = 8 bf16)
    constexpr int GPB = 256 / LPN;         // groups per block
    constexpr int NPB = GPB * T;           // nodes per block
    constexpr int RS  = FOUT / 8;          // row stride in uint4
    __shared__ float ssum[FOUT], ssq[FOUT];
    for (int i = threadIdx.x; i < FOUT; i += 256) { ssum[i] = 0.f; ssq[i] = 0.f; }
    __syncthreads();
    const int grp = threadIdx.x / LPN;
    const int fq  = threadIdx.x % LPN;
    const uint4* hw4 = (const uint4*)hwb;

    int nd[T], jp[T];
    float acc[T][8];
    #pragma unroll
    for (int t = 0; t < T; ++t) {
        nd[t] = blockIdx.x * NPB + grp * T + t;
        jp[t] = (nd[t] < n) ? rp[nd[t]] : 0;
        #pragma unroll
        for (int i = 0; i < 8; ++i) acc[t][i] = 0.f;
    }

    for (int b = 0; b < nbuck; ++b) {
        int je[T];
        #pragma unroll
        for (int t = 0; t < T; ++t)
            je[t] = (nd[t] < n) ? cursor4[(nd[t] << 3) + b] : 0;
        bool more = (jp[0] < je[0]);
        #pragma unroll
        for (int t = 1; t < T; ++t) more |= (jp[t] < je[t]);
        while (more) {
            more = false;
            uint idx[T];
            bool act[T];
            #pragma unroll
            for (int t = 0; t < T; ++t) {             // T independent index loads
                act[t] = jp[t] < je[t];
                idx[t] = epack[act[t] ? jp[t] : 0];
            }
            uint4 q[T];
            #pragma unroll
            for (int t = 0; t < T; ++t) {             // T independent row gathers
                int row = act[t] ? (int)idx[t] : min(nd[t], n - 1);  // dummy = own row (L1-hot)
                q[t] = hw4[(long long)row * RS + fq];
            }
            #pragma unroll
            for (int t = 0; t < T; ++t) {
                if (act[t]) {
                    add8(q[t], acc[t]);
                    ++jp[t];
                    more |= (jp[t] < je[t]);
                }
            }
        }
    }

    // epilogue: + self term, * dis, + bias, write y, BN stats
    float lsum[8] = {0,0,0,0,0,0,0,0}, lsq[8] = {0,0,0,0,0,0,0,0};
    float b8[8];
    #pragma unroll
    for (int i = 0; i < 8; ++i) b8[i] = bias[fq * 8 + i];
    #pragma unroll
    for (int t = 0; t < T; ++t) {
        int node = nd[t];
        if (node < n) {
            uint4 qs = hw4[(long long)node * RS + fq];
            add8(qs, acc[t]);                  // + hw'[d] (self term)
            float dv = dis[node];
            #pragma unroll
            for (int i = 0; i < 8; ++i) acc[t][i] = fmaf(dv, acc[t][i], b8[i]);
            float4* y4 = (float4*)y;
            long long o = (long long)node * (FOUT / 4) + fq * 2;
            y4[o]     = make_float4(acc[t][0], acc[t][1], acc[t][2], acc[t][3]);
            y4[o + 1] = make_float4(acc[t][4], acc[t][5], acc[t][6], acc[t][7]);
            #pragma unroll
            for (int i = 0; i < 8; ++i) {
                lsum[i] += acc[t][i];
                lsq[i] = fmaf(acc[t][i], acc[t][i], lsq[i]);
            }
        }
    }
    #pragma unroll
    for (int i = 0; i < 8; ++i) {
        atomicAdd(&ssum[fq * 8 + i], lsum[i]);
        atomicAdd(&ssq[fq * 8 + i], lsq[i]);
    }
    __syncthreads();
    float* st = stats + ((blockIdx.x & (SREP - 1)) << 7);
    for (int i = threadIdx.x; i < FOUT; i += 256) {
        atomicAdd(&st[i], ssum[i]);
        atomicAdd(&st[64 + i], ssq[i]);
    }
}

// ------- full-range CSR aggregation, flat 8-deep (layer 3: 3.2MB table L2-fits) ------
template <int FOUT>
__global__ __launch_bounds__(256) void k_agg(const u16* __restrict__ hwb,
                                             const uint* __restrict__ epack,
                                             const int* __restrict__ rp,
                                             const float* __restrict__ dis,
                                             const float* __restrict__ bias,
                                             float* __restrict__ y,
                                             float* __restrict__ stats, int n) {
    constexpr int LPN = FOUT / 8;
    constexpr int NPB = 256 / LPN;
    constexpr int RS  = FOUT / 8;
    __shared__ float ssum[FOUT], ssq[FOUT];
    for (int i = threadIdx.x; i < FOUT; i += 256) { ssum[i] = 0.f; ssq[i] = 0.f; }
    __syncthreads();
    const int local = threadIdx.x / LPN;
    const int fq = threadIdx.x % LPN;
    const uint4* hw4 = (const uint4*)hwb;
    float b8[8];
    #pragma unroll
    for (int i = 0; i < 8; ++i) b8[i] = bias[fq * 8 + i];
    float lsum[8] = {0,0,0,0,0,0,0,0}, lsq[8] = {0,0,0,0,0,0,0,0};

    int node = blockIdx.x * NPB + local;
    if (node < n) {
        int j0 = rp[node], j1 = rp[node + 1];
        float acc[8] = {0,0,0,0,0,0,0,0};
        int j = j0;
        for (; j + 8 <= j1; j += 8) {
            uint s0 = epack[j + 0], s1 = epack[j + 1], s2 = epack[j + 2], s3 = epack[j + 3];
            uint s4 = epack[j + 4], s5 = epack[j + 5], s6 = epack[j + 6], s7 = epack[j + 7];
            uint4 q0 = hw4[(long long)s0 * RS + fq];
            uint4 q1 = hw4[(long long)s1 * RS + fq];
            uint4 q2 = hw4[(long long)s2 * RS + fq];
            uint4 q3 = hw4[(long long)s3 * RS + fq];
            uint4 q4 = hw4[(long long)s4 * RS + fq];
            uint4 q5 = hw4[(long long)s5 * RS + fq];
            uint4 q6 = hw4[(long long)s6 * RS + fq];
            uint4 q7 = hw4[(long long)s7 * RS + fq];
            add8(q0, acc); add8(q1, acc); add8(q2, acc); add8(q3, acc);
            add8(q4, acc); add8(q5, acc); add8(q6, acc); add8(q7, acc);
        }
        for (; j + 2 <= j1; j += 2) {
            uint s0 = epack[j + 0], s1 = epack[j + 1];
            uint4 q0 = hw4[(long long)s0 * RS + fq];
            uint4 q1 = hw4[(long long)s1 * RS + fq];
            add8(q0, acc); add8(q1, acc);
        }
        for (; j < j1; ++j) {
            uint4 q = hw4[(long long)epack[j] * RS + fq];
            add8(q, acc);
        }
        uint4 qs = hw4[(long long)node * RS + fq];
        add8(qs, acc);
        float dv = dis[node];
        #pragma unroll
        for (int i = 0; i < 8; ++i) acc[i] = fmaf(dv, acc[i], b8[i]);
        float4* y4 = (float4*)y;
        long long o = (long long)node * (FOUT / 4) + fq * 2;
        y4[o]     = make_float4(acc[0], acc[1], acc[2], acc[3]);
        y4[o + 1] = make_float4(acc[4], acc[5], acc[6], acc[7]);
        #pragma unroll
        for (int i = 0; i < 8; ++i) {
            lsum[i] += acc[i];
            lsq[i] = fmaf(acc[i], acc[i], lsq[i]);
        }
    }
    #pragma unroll
    for (int i = 0; i < 8; ++i) {
        atomicAdd(&ssum[fq * 8 + i], lsum[i]);
        atomicAdd(&ssq[fq * 8 + i], lsq[i]);
    }
    __syncthreads();
    float* st = stats + ((blockIdx.x & (SREP - 1)) << 7);
    for (int i = threadIdx.x; i < FOUT; i += 256) {
        atomicAdd(&st[i], ssum[i]);
        atomicAdd(&st[64 + i], ssq[i]);
    }
}

// -------- pooling (fused BN-apply+LeakyReLU): 8 blocks per graph (512 blocks,
// R9-verified win vs 64-block launch); partials reduced in k_head ----
__global__ void k_pool_graph(const float* __restrict__ yraw, const int* __restrict__ batch,
                             const float* __restrict__ stats, const float* __restrict__ gma,
                             const float* __restrict__ bta, int n,
                             float* __restrict__ psum, float* __restrict__ pmax,
                             float* __restrict__ pcnt) {
    const int g    = blockIdx.x >> 3;
    const int part = blockIdx.x & 7;
    const int f = threadIdx.x & 15;
    float s = 0.f, q = 0.f;
    #pragma unroll 8
    for (int r = 0; r < SREP; ++r) {
        s += stats[(r << 7) + f];
        q += stats[(r << 7) + 64 + f];
    }
    float inv_n = 1.0f / (float)n;
    float m = s * inv_n;
    float var = fmaxf(q * inv_n - m * m, 0.f);
    float sc = rsqrtf(var + 1e-5f) * gma[f];
    float sh = bta[f] - m * sc;

    __shared__ int s_lo, s_hi;
    if (threadIdx.x == 0) {
        int lo = 0, hi = n;
        while (lo < hi) { int mid = (lo + hi) >> 1; if (batch[mid] < g) lo = mid + 1; else hi = mid; }
        s_lo = lo;
        hi = n;
        while (lo < hi) { int mid = (lo + hi) >> 1; if (batch[mid] < g + 1) lo = mid + 1; else hi = mid; }
        s_hi = lo;
    }
    __syncthreads();
    const int gs = s_lo, len = s_hi - s_lo;
    const int start = gs + (int)(((long long)len * part) >> 3);
    const int end   = gs + (int)(((long long)len * (part + 1)) >> 3);
    float lsum = 0.f, lmax = -3.0e38f;
    for (long long idx = (long long)start * 16 + threadIdx.x; idx < (long long)end * 16; idx += blockDim.x) {
        float t = fmaf(yraw[idx], sc, sh);
        float v = t > 0.f ? t : 0.1f * t;
        lsum += v;
        lmax = fmaxf(lmax, v);
    }
    __shared__ float ss[256], sm[256];
    ss[threadIdx.x] = lsum; sm[threadIdx.x] = lmax;
    __syncthreads();
    for (int off = 128; off >= 16; off >>= 1) {
        if (threadIdx.x < off) {
            ss[threadIdx.x] += ss[threadIdx.x + off];
            sm[threadIdx.x] = fmaxf(sm[threadIdx.x], sm[threadIdx.x + off]);
        }
        __syncthreads();
    }
    if (threadIdx.x < 16) {
        psum[(((g << 3) + part) << 4) + threadIdx.x] = ss[threadIdx.x];
        pmax[(((g << 3) + part) << 4) + threadIdx.x] = sm[threadIdx.x];
    }
    if (threadIdx.x == 0) pcnt[(g << 3) + part] = (float)(end - start);
}

// ---------------- head (reduces the 8 pooling partials per graph) ----------------
__global__ void k_head(const float* __restrict__ psum, const float* __restrict__ pmax,
                       const float* __restrict__ pcnt,
                       const float* __restrict__ attn_w, const float* __restrict__ attn_b,
                       const float* __restrict__ fc1_w, const float* __restrict__ fc1_b,
                       const float* __restrict__ fc2_w, const float* __restrict__ fc2_b,
                       const float* __restrict__ out_w, const float* __restrict__ out_b,
                       float* __restrict__ out) {
    int g = threadIdx.x;
    if (g >= GG) return;
    float xs[16], xm[16], xx[16];
    float c = 0.f;
    for (int p = 0; p < 8; ++p) c += pcnt[(g << 3) + p];
    c = fmaxf(c, 1.0f);
    for (int f = 0; f < 16; ++f) { xs[f] = 0.f; xx[f] = -3.0e38f; }
    for (int p = 0; p < 8; ++p) {
        for (int f = 0; f < 16; ++f) {
            xs[f] += psum[(((g << 3) + p) << 4) + f];
            xx[f] = fmaxf(xx[f], pmax[(((g << 3) + p) << 4) + f]);
        }
    }
    for (int f = 0; f < 16; ++f) xm[f] = xs[f] / c;
    float lg[3];
    for (int cI = 0; cI < 3; ++cI) {
        float a = attn_b[cI];
        for (int f = 0; f < 16; ++f) {
            a += xm[f] * attn_w[f * 3 + cI];
            a += xx[f] * attn_w[(16 + f) * 3 + cI];
            a += xs[f] * attn_w[(32 + f) * 3 + cI];
        }
        lg[cI] = a;
    }
    float mx = fmaxf(lg[0], fmaxf(lg[1], lg[2]));
    float e0 = expf(lg[0] - mx), e1 = expf(lg[1] - mx), e2 = expf(lg[2] - mx);
    float inv = 1.0f / (e0 + e1 + e2);
    float a0 = e0 * inv, a1 = e1 * inv, a2 = e2 * inv;
    float xg[16];
    for (int f = 0; f < 16; ++f) xg[f] = a0 * xm[f] + a1 * xx[f] + a2 * xs[f];
    float t1[16];
    for (int j = 0; j < 16; ++j) {
        float a = fc1_b[j];
        for (int k = 0; k < 16; ++k) a += xg[k] * fc1_w[k * 16 + j];
        t1[j] = a > 0.f ? a : 0.1f * a;
    }
    float t2[8];
    for (int j = 0; j < 8; ++j) {
        float a = fc2_b[j];
        for (int k = 0; k < 16; ++k) a += t1[k] * fc2_w[k * 8 + j];
        t2[j] = a > 0.f ? a : 0.1f * a;
    }
    float o = out_b[0];
    for (int k = 0; k < 8; ++k) o += t2[k] * out_w[k];
    o = 1.0f / (1.0f + expf(-o));
    out[g] = o;
}

extern "C" void kernel_launch(void* const* d_in, const int* in_sizes, int n_in,
                              void* d_out, int out_size, void* d_ws, size_t ws_size,
                              hipStream_t stream) {
    const float* x      = (const float*)d_in[0];
    const float* W1     = (const float*)d_in[1];  const float* b1   = (const float*)d_in[2];
    const float* W2     = (const float*)d_in[3];  const float* b2   = (const float*)d_in[4];
    const float* W3     = (const float*)d_in[5];  const float* b3   = (const float*)d_in[6];
    const float* g1     = (const float*)d_in[7];  const float* be1  = (const float*)d_in[8];
    const float* g2     = (const float*)d_in[9];  const float* be2  = (const float*)d_in[10];
    const float* g3     = (const float*)d_in[11]; const float* be3  = (const float*)d_in[12];
    const float* attn_w = (const float*)d_in[13]; const float* attn_b = (const float*)d_in[14];
    const float* fc1_w  = (const float*)d_in[15]; const float* fc1_b  = (const float*)d_in[16];
    const float* fc2_w  = (const float*)d_in[17]; const float* fc2_b  = (const float*)d_in[18];
    const float* out_w  = (const float*)d_in[19]; const float* out_b  = (const float*)d_in[20];
    const int* edge_index = (const int*)d_in[21];
    const int* batch      = (const int*)d_in[22];

    const int N = in_sizes[0] / 128;
    const int E = in_sizes[21] / 2;
    const int* srcp = edge_index;
    const int* dstp = edge_index + E;
    const int nb = (N + 255) / 256;
    const int NBUCK = min((N + (1 << BSH) - 1) >> BSH, 8);

    char* ws = (char*)d_ws;
    float* dis    = (float*)(ws);                 // N f32
    int*   rp     = (int*)(ws + 0x100000);        // N+1 int
    int*   bsum   = (int*)(ws + 0x180000);        // <=512 int (2KB)
    float* stats1 = (float*)(ws + 0x180800);      // SREP*128 f32 = 16KB per layer
    float* stats2 = (float*)(ws + 0x184800);
    float* stats3 = (float*)(ws + 0x188800);
    float* psum   = (float*)(ws + 0x80000);       // 64*8*16 f32 = 32KB
    float* pmax   = psum + GG * 8 * 16;           // 32KB
    float* pcnt   = pmax + GG * 8 * 16;           // 2KB
    int*   cnt4    = (int*)(ws + 0x190000);       // 8N int
    int*   cursor4 = cnt4 + (size_t)8 * N;        // 8N int
    uint*  epack   = (uint*)(cursor4 + (size_t)8 * N);   // E uint
    float* buf1    = (float*)((char*)epack + (((size_t)E * 4 + 255) & ~(size_t)255));
    u16*   hwb     = (u16*)(buf1 + (size_t)N * 64);

    // ---- bucketed CSR build (atomic kernels XCD-partitioned) ----
    hipMemsetAsync(cnt4, 0, (size_t)N * 32, stream);
    k_hist<<<2048, 256, 0, stream>>>(srcp, dstp, cnt4, E, N);
    k_scanA<<<nb, 256, 0, stream>>>(cnt4, rp, bsum, dis, N);   // fused degree+dis+scan
    k_scanB<<<1, 512, 0, stream>>>(bsum, nb);
    k_scanC<<<nb, 256, 0, stream>>>(rp, bsum, cnt4, cursor4, N, E);
    hipMemsetAsync(stats1, 0, 3 * SREP * 512, stream);

    // ---- fused: scatter (atomic-bound) overlapped with layer-1 GEMM (BW/FLOP) ----
    k_scat_mm<<<2048 + (N + 63) / 64, 256, 0, stream>>>(
        srcp, dstp, cursor4, epack, E, N, x, W1, dis, hwb);
    k_aggt<64, 4><<<(N + 127) / 128, 256, 0, stream>>>(
        hwb, epack, rp, cursor4, dis, b1, buf1, stats1, N, NBUCK);

    // ---- layer 2 (BN1+lrelu fused into staging); transposed bucketed agg ----
    k_mm<64, 32, true><<<(N + 127) / 128, 256, 0, stream>>>(
        buf1, W2, dis, stats1, g1, be1, hwb, N);
    k_aggt<32, 4><<<(N + 255) / 256, 256, 0, stream>>>(
        hwb, epack, rp, cursor4, dis, b2, buf1, stats2, N, NBUCK);

    // ---- layer 3 (BN2+lrelu fused); table fits L2, flat 8-deep agg ----
    k_mm<32, 16, true><<<(N + 255) / 256, 256, 0, stream>>>(
        buf1, W3, dis, stats2, g2, be2, hwb, N);
    k_agg<16><<<(N + 127) / 128, 256, 0, stream>>>(hwb, epack, rp, dis, b3, buf1, stats3, N);

    // ---- pooling (BN3+lrelu fused, 8 blocks/graph) + head (reduces partials) ----
    k_pool_graph<<<GG * 8, 256, 0, stream>>>(buf1, batch, stats3, g3, be3, N, psum, pmax, pcnt);
    k_head<<<1, 64, 0, stream>>>(psum, pmax, pcnt, attn_w, attn_b,
                                 fc1_w, fc1_b, fc2_w, fc2_b, out_w, out_b,
                                 (float*)d_out);
}